// Round 1
// baseline (1401.695 us; speedup 1.0000x reference)
//
#include <hip/hip_runtime.h>

// B=32, N_IN=2048, K_OUT=128, C=16, D=16, 3 routing iters.
// Per iter: [k_logits: MFMA u-tiles -> softmax p], [k_acc: MFMA weighted sum -> slice partials],
// [k_fin: slice-reduce + squash -> transposed tables / output].
// u_hat recomputed from W each pass (W=268MB < u_hat=537MB). MFMA hi/lo trick (verified R3):
// K=32 packed as [c_hi | c_lo]: B=[W_hi|W_lo], A1=[x_hi|x_hi], A2=[x_lo|x_lo]
// -> 2 MFMAs give the full (W_hi+W_lo)(x_hi+x_lo) ~= exact fp32 product.
// NOTE: no second __launch_bounds__ arg anywhere -- R3 showed it acts as a hard VGPR cap.
//
// NEW (this round): one-time prologue packs W and x into the EXACT per-lane MFMA fragments
// (bitwise-identical to in-kernel pack_B/pack_A), so the 5 W-streaming passes become pure
// {dwordx4 load -> MFMA} with no bit-twiddle VALU chain. Guarded by ws_size; falls back to
// the verified in-kernel-packing path if the workspace is too small.

typedef __attribute__((ext_vector_type(8))) short  s16x8;
typedef __attribute__((ext_vector_type(4))) float  f32x4;

#define NSLICE 64

__device__ __forceinline__ unsigned bf16rn(float f) {
    const unsigned u = __builtin_bit_cast(unsigned, f);
    return (u + 0x7fffu + ((u >> 16) & 1u)) >> 16;
}
__device__ __forceinline__ unsigned pack2rn(float a, float b) {
    return bf16rn(a) | (bf16rn(b) << 16);
}
__device__ __forceinline__ unsigned phi(float a, float b) {   // truncation hi-pack
    return (__builtin_bit_cast(unsigned, a) >> 16) | (__builtin_bit_cast(unsigned, b) & 0xffff0000u);
}
__device__ __forceinline__ unsigned plo(float a, float b) {   // residual lo-pack
    const float la = a - __builtin_bit_cast(float, __builtin_bit_cast(unsigned, a) & 0xffff0000u);
    const float lb = b - __builtin_bit_cast(float, __builtin_bit_cast(unsigned, b) & 0xffff0000u);
    return pack2rn(la, lb);
}

// A-frags for one b-group: A1=[x_hi|x_hi], A2=[x_lo|x_lo]; xp points at x[b][i][oct]
__device__ __forceinline__ void pack_A(const float* __restrict__ xp, s16x8& A1, s16x8& A2) {
    const float4 x0 = *(const float4*)xp;
    const float4 x1 = *(const float4*)(xp + 4);
    uint4 h, l;
    h.x = phi(x0.x, x0.y); h.y = phi(x0.z, x0.w);
    h.z = phi(x1.x, x1.y); h.w = phi(x1.z, x1.w);
    l.x = plo(x0.x, x0.y); l.y = plo(x0.z, x0.w);
    l.z = plo(x1.x, x1.y); l.w = plo(x1.z, x1.w);
    A1 = __builtin_bit_cast(s16x8, h);
    A2 = __builtin_bit_cast(s16x8, l);
}

// B-frag [W_hi|W_lo]: wp points at W[i][k][d=n][oct]; sel=true -> hi half lanes
__device__ __forceinline__ s16x8 pack_B(const float* __restrict__ wp, bool sel) {
    const float4 w0 = *(const float4*)wp;
    const float4 w1 = *(const float4*)(wp + 4);
    const float f[8] = {w0.x, w0.y, w0.z, w0.w, w1.x, w1.y, w1.z, w1.w};
    float t[8];
#pragma unroll
    for (int j = 0; j < 8; ++j) {
        const float hf = __builtin_bit_cast(float, __builtin_bit_cast(unsigned, f[j]) & 0xffff0000u);
        t[j] = sel ? hf : (f[j] - hf);
    }
    uint4 bw;
    bw.x = pack2rn(t[0], t[1]);
    bw.y = pack2rn(t[2], t[3]);
    bw.z = pack2rn(t[4], t[5]);
    bw.w = pack2rn(t[6], t[7]);
    return __builtin_bit_cast(s16x8, bw);
}

__device__ __forceinline__ f32x4 sx4(f32x4 v, int m) {
    f32x4 r;
    r.x = __shfl_xor(v.x, m, 64);
    r.y = __shfl_xor(v.y, m, 64);
    r.z = __shfl_xor(v.z, m, 64);
    r.w = __shfl_xor(v.w, m, 64);
    return r;
}

// ---------------------------------------------------------------------------
// Prologue packers: materialize the EXACT fragments the consumers need.
// Wp[(i*128+k)*64 + lane]          = pack_B(W[i][k] @ lane cfg)        (16B/lane, 1KB/wave coalesced)
// xA[((i*2+bg)*64 + lane)*2 + h]   = A1 (h=0) / A2 (h=1) for (i,bg)
__global__ __launch_bounds__(256) void k_packW(const float* __restrict__ W,
                                               s16x8* __restrict__ Wp)
{
    const size_t gid = (size_t)blockIdx.x * 256 + threadIdx.x;
    const size_t ik  = gid >> 6;                 // i*128+k, 0..262143
    const int lane = threadIdx.x & 63;
    const int n    = lane & 15, q = lane >> 4;
    const int oct  = (q & 1) * 8;
    const bool sel = (q < 2);
    Wp[ik * 64 + lane] = pack_B(W + ik * 256 + n * 16 + oct, sel);
}

__global__ __launch_bounds__(256) void k_packX(const float* __restrict__ x,
                                               s16x8* __restrict__ xA)
{
    const int wid  = blockIdx.x * 4 + (threadIdx.x >> 6);   // 0..4095 = i*2+bg
    const int lane = threadIdx.x & 63;
    const int i  = wid >> 1, bg = wid & 1;
    const int n  = lane & 15, q = lane >> 4;
    const int oct = (q & 1) * 8;
    s16x8 A1, A2;
    pack_A(x + ((size_t)(bg * 16 + n) * 2048 + i) * 16 + oct, A1, A2);
    s16x8* o = xA + ((size_t)wid * 64 + lane) * 2;
    o[0] = A1;
    o[1] = A2;
}

// ---------------------------------------------------------------------------
// out_sl[s][b][k][d] = sum_{i in slice s} w(b,i,k)*u_hat(b,i,k,d); w=p or 1.
// wave = (2-k set) x (32-i slice), all 32 b. 4096 waves (4/SIMD). No atomics.
template<bool USE_P, bool PK>
__global__ __launch_bounds__(256) void k_acc(const float* __restrict__ W,
                                             const float* __restrict__ x,
                                             const s16x8* __restrict__ Wp,
                                             const s16x8* __restrict__ xA,
                                             const float* __restrict__ p,     // [i][k][b]
                                             float* __restrict__ out_sl)      // [s][b][k][d]
{
    const int w    = blockIdx.x * 4 + (threadIdx.x >> 6);   // 0..4095
    const int lane = threadIdx.x & 63;
    const int n    = lane & 15;          // A row m=b_local ; B col n=d ; C/D col=d
    const int q    = lane >> 4;
    const int oct  = (q & 1) * 8;
    const bool sel = (q < 2);
    const int k0    = (w & 63) * 2;
    const int slice = w >> 6;            // 0..63
    const int i0    = slice * 32;

    const f32x4 zero = {0.f, 0.f, 0.f, 0.f};
    f32x4 acc[2][2];
#pragma unroll
    for (int kp = 0; kp < 2; ++kp)
#pragma unroll
        for (int bg = 0; bg < 2; ++bg) acc[kp][bg] = zero;

#pragma unroll 1
    for (int i = i0; i < i0 + 32; ++i) {
        s16x8 A1[2], A2[2];
        if constexpr (PK) {
            const s16x8* xp = xA + ((size_t)i * 2 * 64 + lane) * 2;
            A1[0] = xp[0];   A2[0] = xp[1];
            A1[1] = xp[128]; A2[1] = xp[129];
        } else {
#pragma unroll
            for (int bg = 0; bg < 2; ++bg)
                pack_A(x + ((size_t)(bg * 16 + n) * 2048 + i) * 16 + oct, A1[bg], A2[bg]);
        }
#pragma unroll
        for (int kp = 0; kp < 2; ++kp) {
            const int k = k0 + kp;
            const s16x8 Bf = PK ? Wp[((size_t)i * 128 + k) * 64 + lane]
                                : pack_B(W + (size_t)i * 32768 + (size_t)k * 256 + n * 16 + oct, sel);
#pragma unroll
            for (int bg = 0; bg < 2; ++bg) {
                if (USE_P) {
                    f32x4 u = __builtin_amdgcn_mfma_f32_16x16x32_bf16(A1[bg], Bf, zero, 0, 0, 0);
                    u       = __builtin_amdgcn_mfma_f32_16x16x32_bf16(A2[bg], Bf, u,    0, 0, 0);
                    const float4 pv = *(const float4*)(p + ((size_t)i * 128 + k) * 32 + bg * 16 + 4 * q);
                    acc[kp][bg].x = fmaf(pv.x, u.x, acc[kp][bg].x);
                    acc[kp][bg].y = fmaf(pv.y, u.y, acc[kp][bg].y);
                    acc[kp][bg].z = fmaf(pv.z, u.z, acc[kp][bg].z);
                    acc[kp][bg].w = fmaf(pv.w, u.w, acc[kp][bg].w);
                } else {
                    acc[kp][bg] = __builtin_amdgcn_mfma_f32_16x16x32_bf16(A1[bg], Bf, acc[kp][bg], 0, 0, 0);
                    acc[kp][bg] = __builtin_amdgcn_mfma_f32_16x16x32_bf16(A2[bg], Bf, acc[kp][bg], 0, 0, 0);
                }
            }
        }
    }
#pragma unroll
    for (int kp = 0; kp < 2; ++kp)
#pragma unroll
        for (int bg = 0; bg < 2; ++bg)
#pragma unroll
            for (int r = 0; r < 4; ++r) {
                const int b = bg * 16 + 4 * q + r;   // C/D row = 4*quad + reg (verified R3)
                out_sl[(((size_t)slice * 32 + b) * 128 + (k0 + kp)) * 16 + n] = acc[kp][bg][r];
            }
}

// ---------------------------------------------------------------------------
// MFMA logits: block = 8 waves, wave wv covers k = wv*16+kp (16 k's), 4 i's per block.
// Per (i,kp): u tile via MFMA pair; s2 += u*u, dot += u*V in-lane; butterfly over 16
// d-lanes; exp; block softmax over all 128 k via LDS; p written [i][k][b] (float4).
template<bool PK>
__global__ __launch_bounds__(512) void k_logits(const float* __restrict__ W,
                                                const float* __restrict__ x,
                                                const s16x8* __restrict__ Wp,
                                                const s16x8* __restrict__ xA,
                                                const float* __restrict__ Vbt,  // [k][d][b]
                                                const float* __restrict__ Nt,   // [k][b]
                                                const float T,
                                                float* __restrict__ pbuf,       // [i][k][b]
                                                float* __restrict__ colsum)     // [b][k]
{
    __shared__ __align__(16) float e_s[8][16][32];
    __shared__ __align__(16) float den_s[8][32];
    __shared__ float denom_s[32];
    const int tid  = threadIdx.x;
    const int wv   = tid >> 6, lane = tid & 63;
    const int n    = lane & 15, q = lane >> 4;
    const int oct  = (q & 1) * 8;
    const bool sel = (q < 2);
    const f32x4 zero = {0.f, 0.f, 0.f, 0.f};

    // p-write phase mapping: thread -> (k = tid/4, b0 = (tid&3)*8)
    const int pk = tid >> 2;
    const int pb = (tid & 3) * 8;
    float cs[8];
#pragma unroll
    for (int j = 0; j < 8; ++j) cs[j] = 0.f;

    const int i0 = blockIdx.x * 4;
#pragma unroll 1
    for (int ii = 0; ii < 4; ++ii) {
        const int i = i0 + ii;
        s16x8 A1[2], A2[2];
        if constexpr (PK) {
            const s16x8* xp = xA + ((size_t)i * 2 * 64 + lane) * 2;
            A1[0] = xp[0];   A2[0] = xp[1];
            A1[1] = xp[128]; A2[1] = xp[129];
        } else {
#pragma unroll
            for (int bg = 0; bg < 2; ++bg)
                pack_A(x + ((size_t)(bg * 16 + n) * 2048 + i) * 16 + oct, A1[bg], A2[bg]);
        }

        f32x4 den[2] = {zero, zero};
#pragma unroll
        for (int kp = 0; kp < 16; ++kp) {
            const int k = wv * 16 + kp;
            const s16x8 Bf = PK ? Wp[((size_t)i * 128 + k) * 64 + lane]
                                : pack_B(W + (size_t)i * 32768 + (size_t)k * 256 + n * 16 + oct, sel);
            f32x4 s2v[2], dtv[2];
#pragma unroll
            for (int bg = 0; bg < 2; ++bg) {
                f32x4 u = __builtin_amdgcn_mfma_f32_16x16x32_bf16(A1[bg], Bf, zero, 0, 0, 0);
                u       = __builtin_amdgcn_mfma_f32_16x16x32_bf16(A2[bg], Bf, u,    0, 0, 0);
                const float4 Vv = *(const float4*)(Vbt + ((size_t)k * 16 + n) * 32 + bg * 16 + 4 * q);
                s2v[bg].x = u.x * u.x; s2v[bg].y = u.y * u.y; s2v[bg].z = u.z * u.z; s2v[bg].w = u.w * u.w;
                dtv[bg].x = u.x * Vv.x; dtv[bg].y = u.y * Vv.y; dtv[bg].z = u.z * Vv.z; dtv[bg].w = u.w * Vv.w;
            }
#pragma unroll
            for (int m = 1; m < 16; m <<= 1) {
#pragma unroll
                for (int bg = 0; bg < 2; ++bg) {
                    s2v[bg] += sx4(s2v[bg], m);
                    dtv[bg] += sx4(dtv[bg], m);
                }
            }
#pragma unroll
            for (int bg = 0; bg < 2; ++bg) {
                const float4 Nv = *(const float4*)(Nt + (size_t)k * 32 + bg * 16 + 4 * q);
                f32x4 e;
#pragma unroll
                for (int r = 0; r < 4; ++r) {
                    const float ss  = s2v[bg][r];
                    const float inv = 1.0f / (0.5f + ss);
                    const float scl = sqrtf(ss) * inv;
                    const float fq  = ss * ss * inv * inv;
                    const float Nr  = (r == 0) ? Nv.x : (r == 1) ? Nv.y : (r == 2) ? Nv.z : Nv.w;
                    e[r] = __expf(T * (1.0f - fq) + 2.0f * scl * dtv[bg][r] - Nr);
                }
                den[bg] += e;
                if (n == 0) *(f32x4*)&e_s[wv][kp][bg * 16 + 4 * q] = e;
            }
        }
        if (n == 0) {
#pragma unroll
            for (int bg = 0; bg < 2; ++bg)
                *(f32x4*)&den_s[wv][bg * 16 + 4 * q] = den[bg];
        }
        __syncthreads();
        if (tid < 32) {
            float s = 0.f;
#pragma unroll
            for (int w2 = 0; w2 < 8; ++w2) s += den_s[w2][tid];
            denom_s[tid] = s;
        }
        __syncthreads();
        {
            const float4 e0 = *(const float4*)&e_s[pk >> 4][pk & 15][pb];
            const float4 e1 = *(const float4*)&e_s[pk >> 4][pk & 15][pb + 4];
            const float4 d0 = *(const float4*)&denom_s[pb];
            const float4 d1 = *(const float4*)&denom_s[pb + 4];
            float4 p0, p1;
            p0.x = e0.x / d0.x; p0.y = e0.y / d0.y; p0.z = e0.z / d0.z; p0.w = e0.w / d0.w;
            p1.x = e1.x / d1.x; p1.y = e1.y / d1.y; p1.z = e1.z / d1.z; p1.w = e1.w / d1.w;
            cs[0] += p0.x; cs[1] += p0.y; cs[2] += p0.z; cs[3] += p0.w;
            cs[4] += p1.x; cs[5] += p1.y; cs[6] += p1.z; cs[7] += p1.w;
            *(float4*)(pbuf + ((size_t)i * 128 + pk) * 32 + pb)     = p0;
            *(float4*)(pbuf + ((size_t)i * 128 + pk) * 32 + pb + 4) = p1;
        }
        __syncthreads();
    }
#pragma unroll
    for (int j = 0; j < 8; ++j) atomicAdd(colsum + (size_t)(pb + j) * 128 + pk, cs[j]);
}

// ---------------------------------------------------------------------------
// Sum 64 slices -> v = squash(raw/colsum); write transposed tables (mode 0/1) or output.
__global__ __launch_bounds__(256) void k_fin(const float* __restrict__ raw_sl,
                                             const float* __restrict__ colsum,
                                             const float* __restrict__ Vbt_prev,
                                             const float* __restrict__ Nt_prev,
                                             float* __restrict__ Vbt_out,
                                             float* __restrict__ Nt_out,
                                             float* __restrict__ out,
                                             const int mode)
{
    const int tid = threadIdx.x;
    const int t   = blockIdx.x * 16 + (tid >> 4);   // (b,k): b=t>>7, k=t&127
    const int d   = tid & 15;
    const int b   = t >> 7, k = t & 127;
    float s = 0.f;
#pragma unroll 4
    for (int sl = 0; sl < NSLICE; ++sl) s += raw_sl[(size_t)sl * 65536 + (size_t)t * 16 + d];
    const float invcs = (mode == 0) ? (1.0f / 2048.0f) : 1.0f / colsum[t];
    const float v = s * invcs;
    float s2 = v * v;
#pragma unroll
    for (int m = 1; m < 16; m <<= 1) s2 += __shfl_xor(s2, m, 64);
    const float inv = 1.0f / (0.5f + s2);
    const float scl = sqrtf(s2) * inv;
    if (mode == 0) {
        Vbt_out[((size_t)k * 16 + d) * 32 + b] = scl * v;
        if (d == 0) Nt_out[(size_t)k * 32 + b] = s2 * scl * scl;
    } else if (mode == 1) {
        Vbt_out[((size_t)k * 16 + d) * 32 + b] = Vbt_prev[((size_t)k * 16 + d) * 32 + b] + scl * v;
        if (d == 0) Nt_out[(size_t)k * 32 + b] = Nt_prev[(size_t)k * 32 + b] + s2 * scl * scl;
    } else {
        out[(size_t)t * 16 + d] = scl * v;
        if (d == 0) out[65536 + t] = s2 * inv;   // ||v|| = s2/(0.5+s2)
    }
}

extern "C" void kernel_launch(void* const* d_in, const int* in_sizes, int n_in,
                              void* d_out, int out_size, void* d_ws, size_t ws_size,
                              hipStream_t stream)
{
    const float* x = (const float*)d_in[0];   // [32][2048][16]
    const float* W = (const float*)d_in[3];   // [2048][128][16][16]; labels = arange -> identity

    float* ws    = (float*)d_ws;
    float* cs1   = ws;                 // 4096 (zeroed)
    float* cs2   = ws + 4096;          // 4096 (zeroed)
    float* Vbt0  = ws + 8192;          // 65536  [k][d][b]
    float* VSbt  = ws + 73728;         // 65536
    float* N1t   = ws + 139264;        // 4096   [k][b]
    float* N2t   = ws + 143360;        // 4096
    float* pbuf  = ws + 147456;        // 8388608 (32MB) [i][k][b]
    float* slces = ws + 8536064;       // 4194304 (16MB) [s][b][k][d]

    // packed fragment tables (appended; 16B-aligned)
    s16x8* Wp = (s16x8*)(ws + 12730368);                       // 268MB: 262144*64 frags
    s16x8* xA = (s16x8*)((short*)Wp + (size_t)134217728);      // 16MB:  4096*64*2 frags
    const size_t needed = (size_t)12730368 * 4                 // base layout bytes
                        + (size_t)134217728 * 2                // Wp bytes
                        + (size_t)8388608 * 2;                 // xA bytes
    const bool pk = (ws_size >= needed);

    (void)hipMemsetAsync(d_ws, 0, 8192 * sizeof(float), stream);

    if (pk) {
        k_packW<<<65536, 256, 0, stream>>>(W, Wp);
        k_packX<<<1024, 256, 0, stream>>>(x, xA);
        // iter 0: v0 = squash(mean_i u_hat)
        k_acc<false, true><<<1024, 256, 0, stream>>>(W, x, Wp, xA, nullptr, slces);
        k_fin<<<256, 256, 0, stream>>>(slces, nullptr, nullptr, nullptr, Vbt0, N1t, nullptr, 0);
        // iter 1
        k_logits<true><<<512, 512, 0, stream>>>(W, x, Wp, xA, Vbt0, N1t, 1.0f, pbuf, cs1);
        k_acc<true, true><<<1024, 256, 0, stream>>>(W, x, Wp, xA, pbuf, slces);
        k_fin<<<256, 256, 0, stream>>>(slces, cs1, Vbt0, N1t, VSbt, N2t, nullptr, 1);
        // iter 2: b2 = dd0+dd1 via summed tables VS=v0+v1, N2=||v0||^2+||v1||^2
        k_logits<true><<<512, 512, 0, stream>>>(W, x, Wp, xA, VSbt, N2t, 2.0f, pbuf, cs2);
        k_acc<true, true><<<1024, 256, 0, stream>>>(W, x, Wp, xA, pbuf, slces);
        k_fin<<<256, 256, 0, stream>>>(slces, cs2, nullptr, nullptr, nullptr, nullptr, (float*)d_out, 2);
    } else {
        // verified fallback: in-kernel packing (identical numerics)
        k_acc<false, false><<<1024, 256, 0, stream>>>(W, x, nullptr, nullptr, nullptr, slces);
        k_fin<<<256, 256, 0, stream>>>(slces, nullptr, nullptr, nullptr, Vbt0, N1t, nullptr, 0);
        k_logits<false><<<512, 512, 0, stream>>>(W, x, nullptr, nullptr, Vbt0, N1t, 1.0f, pbuf, cs1);
        k_acc<true, false><<<1024, 256, 0, stream>>>(W, x, nullptr, nullptr, pbuf, slces);
        k_fin<<<256, 256, 0, stream>>>(slces, cs1, Vbt0, N1t, VSbt, N2t, nullptr, 1);
        k_logits<false><<<512, 512, 0, stream>>>(W, x, nullptr, nullptr, VSbt, N2t, 2.0f, pbuf, cs2);
        k_acc<true, false><<<1024, 256, 0, stream>>>(W, x, nullptr, nullptr, pbuf, slces);
        k_fin<<<256, 256, 0, stream>>>(slces, cs2, nullptr, nullptr, nullptr, nullptr, (float*)d_out, 2);
    }
}

// Round 2
// 858.375 us; speedup vs baseline: 1.6330x; 1.6330x over previous
//
#include <hip/hip_runtime.h>

// B=32, N_IN=2048, K_OUT=128, C=16, D=16, 3 routing iters.
// Per iter: [k_logits: MFMA u-tiles -> softmax p], [k_acc: MFMA weighted sum -> slice partials
// + slice colsum partials], [k_fin: slice-reduce + squash -> transposed tables / output].
// MFMA hi/lo trick (verified R3): K=32 packed as [c_hi | c_lo].
// SWAPPED operands this round: u[d][b] = mfma(Wfrag, xfrag) -- A/B fragment images are
// identical layouts, so packed tables are reused as-is; d lands in the row (register) dim,
// so the d-reduction is 3 in-lane adds + 2 shuffles (xor16, xor32) instead of a 64-shuffle
// butterfly. colsum atomics removed: k_acc writes per-slice colsum partials (no atomics).
// V table stored as [k][d>>2][b][d&3] so each lane's 4 d-values load as one float4.
// NOTE: no second __launch_bounds__ arg anywhere -- R3 showed it acts as a hard VGPR cap.

typedef __attribute__((ext_vector_type(8))) short  s16x8;
typedef __attribute__((ext_vector_type(4))) float  f32x4;

#define NSLICE 64

__device__ __forceinline__ unsigned bf16rn(float f) {
    const unsigned u = __builtin_bit_cast(unsigned, f);
    return (u + 0x7fffu + ((u >> 16) & 1u)) >> 16;
}
__device__ __forceinline__ unsigned pack2rn(float a, float b) {
    return bf16rn(a) | (bf16rn(b) << 16);
}
__device__ __forceinline__ unsigned phi(float a, float b) {   // truncation hi-pack
    return (__builtin_bit_cast(unsigned, a) >> 16) | (__builtin_bit_cast(unsigned, b) & 0xffff0000u);
}
__device__ __forceinline__ unsigned plo(float a, float b) {   // residual lo-pack
    const float la = a - __builtin_bit_cast(float, __builtin_bit_cast(unsigned, a) & 0xffff0000u);
    const float lb = b - __builtin_bit_cast(float, __builtin_bit_cast(unsigned, b) & 0xffff0000u);
    return pack2rn(la, lb);
}

// x-frags for one b-group: X1=[x_hi|x_hi], X2=[x_lo|x_lo]; xp points at x[b][i][oct]
__device__ __forceinline__ void pack_A(const float* __restrict__ xp, s16x8& A1, s16x8& A2) {
    const float4 x0 = *(const float4*)xp;
    const float4 x1 = *(const float4*)(xp + 4);
    uint4 h, l;
    h.x = phi(x0.x, x0.y); h.y = phi(x0.z, x0.w);
    h.z = phi(x1.x, x1.y); h.w = phi(x1.z, x1.w);
    l.x = plo(x0.x, x0.y); l.y = plo(x0.z, x0.w);
    l.z = plo(x1.x, x1.y); l.w = plo(x1.z, x1.w);
    A1 = __builtin_bit_cast(s16x8, h);
    A2 = __builtin_bit_cast(s16x8, l);
}

// W-frag [W_hi|W_lo]: wp points at W[i][k][d=n][oct]; sel=true -> hi half lanes
__device__ __forceinline__ s16x8 pack_B(const float* __restrict__ wp, bool sel) {
    const float4 w0 = *(const float4*)wp;
    const float4 w1 = *(const float4*)(wp + 4);
    const float f[8] = {w0.x, w0.y, w0.z, w0.w, w1.x, w1.y, w1.z, w1.w};
    float t[8];
#pragma unroll
    for (int j = 0; j < 8; ++j) {
        const float hf = __builtin_bit_cast(float, __builtin_bit_cast(unsigned, f[j]) & 0xffff0000u);
        t[j] = sel ? hf : (f[j] - hf);
    }
    uint4 bw;
    bw.x = pack2rn(t[0], t[1]);
    bw.y = pack2rn(t[2], t[3]);
    bw.z = pack2rn(t[4], t[5]);
    bw.w = pack2rn(t[6], t[7]);
    return __builtin_bit_cast(s16x8, bw);
}

// ---------------------------------------------------------------------------
// Prologue packers: materialize the EXACT per-lane MFMA fragments.
__global__ __launch_bounds__(256) void k_packW(const float* __restrict__ W,
                                               s16x8* __restrict__ Wp)
{
    const size_t gid = (size_t)blockIdx.x * 256 + threadIdx.x;
    const size_t ik  = gid >> 6;                 // i*128+k, 0..262143
    const int lane = threadIdx.x & 63;
    const int n    = lane & 15, q = lane >> 4;
    const int oct  = (q & 1) * 8;
    const bool sel = (q < 2);
    Wp[ik * 64 + lane] = pack_B(W + ik * 256 + n * 16 + oct, sel);
}

__global__ __launch_bounds__(256) void k_packX(const float* __restrict__ x,
                                               s16x8* __restrict__ xA)
{
    const int wid  = blockIdx.x * 4 + (threadIdx.x >> 6);   // 0..4095 = i*2+bg
    const int lane = threadIdx.x & 63;
    const int i  = wid >> 1, bg = wid & 1;
    const int n  = lane & 15, q = lane >> 4;
    const int oct = (q & 1) * 8;
    s16x8 A1, A2;
    pack_A(x + ((size_t)(bg * 16 + n) * 2048 + i) * 16 + oct, A1, A2);
    s16x8* o = xA + ((size_t)wid * 64 + lane) * 2;
    o[0] = A1;
    o[1] = A2;
}

// ---------------------------------------------------------------------------
// out_sl[s][b][k][d] = sum_{i in slice s} w(b,i,k)*u_hat(b,i,k,d); w=p or 1.
// Swapped: u tile is [d][b]; lane (q,n) holds d=4q+r (r=0..3), b=n (+16 for bg=1).
// Also writes csl[s][k][b] = sum_{i in slice} p(b,i,k) (USE_P only, no atomics).
template<bool USE_P, bool PK>
__global__ __launch_bounds__(256) void k_acc(const float* __restrict__ W,
                                             const float* __restrict__ x,
                                             const s16x8* __restrict__ Wp,
                                             const s16x8* __restrict__ xA,
                                             const float* __restrict__ p,     // [i][k][b]
                                             float* __restrict__ out_sl,      // [s][b][k][d]
                                             float* __restrict__ csl)         // [s][k][b]
{
    const int w    = blockIdx.x * 4 + (threadIdx.x >> 6);   // 0..4095
    const int lane = threadIdx.x & 63;
    const int n    = lane & 15;
    const int q    = lane >> 4;
    const int oct  = (q & 1) * 8;
    const bool sel = (q < 2);
    const int k0    = (w & 63) * 2;
    const int slice = w >> 6;            // 0..63
    const int i0    = slice * 32;

    const f32x4 zero = {0.f, 0.f, 0.f, 0.f};
    f32x4 acc[2][2];
    float csacc[2][2];
#pragma unroll
    for (int kp = 0; kp < 2; ++kp)
#pragma unroll
        for (int bg = 0; bg < 2; ++bg) { acc[kp][bg] = zero; csacc[kp][bg] = 0.f; }

#pragma unroll 1
    for (int i = i0; i < i0 + 32; ++i) {
        s16x8 X1[2], X2[2];
        if constexpr (PK) {
            const s16x8* xp = xA + ((size_t)i * 2 * 64 + lane) * 2;
            X1[0] = xp[0];   X2[0] = xp[1];
            X1[1] = xp[128]; X2[1] = xp[129];
        } else {
#pragma unroll
            for (int bg = 0; bg < 2; ++bg)
                pack_A(x + ((size_t)(bg * 16 + n) * 2048 + i) * 16 + oct, X1[bg], X2[bg]);
        }
#pragma unroll
        for (int kp = 0; kp < 2; ++kp) {
            const int k = k0 + kp;
            const s16x8 Wf = PK ? Wp[((size_t)i * 128 + k) * 64 + lane]
                                : pack_B(W + (size_t)i * 32768 + (size_t)k * 256 + n * 16 + oct, sel);
#pragma unroll
            for (int bg = 0; bg < 2; ++bg) {
                if (USE_P) {
                    f32x4 u = __builtin_amdgcn_mfma_f32_16x16x32_bf16(Wf, X1[bg], zero, 0, 0, 0);
                    u       = __builtin_amdgcn_mfma_f32_16x16x32_bf16(Wf, X2[bg], u,    0, 0, 0);
                    const float pv = p[((size_t)i * 128 + k) * 32 + bg * 16 + n];
                    acc[kp][bg].x = fmaf(pv, u.x, acc[kp][bg].x);
                    acc[kp][bg].y = fmaf(pv, u.y, acc[kp][bg].y);
                    acc[kp][bg].z = fmaf(pv, u.z, acc[kp][bg].z);
                    acc[kp][bg].w = fmaf(pv, u.w, acc[kp][bg].w);
                    csacc[kp][bg] += pv;
                } else {
                    acc[kp][bg] = __builtin_amdgcn_mfma_f32_16x16x32_bf16(Wf, X1[bg], acc[kp][bg], 0, 0, 0);
                    acc[kp][bg] = __builtin_amdgcn_mfma_f32_16x16x32_bf16(Wf, X2[bg], acc[kp][bg], 0, 0, 0);
                }
            }
        }
    }
#pragma unroll
    for (int kp = 0; kp < 2; ++kp)
#pragma unroll
        for (int bg = 0; bg < 2; ++bg)
            *(f32x4*)(out_sl + (((size_t)slice * 32 + bg * 16 + n) * 128 + (k0 + kp)) * 16 + 4 * q)
                = acc[kp][bg];
    if (USE_P && lane < 16) {
#pragma unroll
        for (int kp = 0; kp < 2; ++kp)
#pragma unroll
            for (int bg = 0; bg < 2; ++bg)
                csl[((size_t)slice * 128 + (k0 + kp)) * 32 + bg * 16 + n] = csacc[kp][bg];
    }
}

// ---------------------------------------------------------------------------
// MFMA logits (swapped): block = 8 waves, wave wv covers k = wv*16+kp, 4 i's per block.
// Per (i,kp,bg): u[d][b] via MFMA pair; s2/dot reduced 4-in-lane + xor16 + xor32;
// exp; block softmax over all 128 k via LDS; p written [i][k][b] (float4). No atomics.
template<bool PK>
__global__ __launch_bounds__(512) void k_logits(const float* __restrict__ W,
                                                const float* __restrict__ x,
                                                const s16x8* __restrict__ Wp,
                                                const s16x8* __restrict__ xA,
                                                const float* __restrict__ Vq,   // [k][d>>2][b][d&3]
                                                const float* __restrict__ Nt,   // [k][b]
                                                const float T,
                                                float* __restrict__ pbuf)       // [i][k][b]
{
    __shared__ __align__(16) float e_s[8][16][32];
    __shared__ __align__(16) float den_s[8][32];
    __shared__ float denom_s[32];
    const int tid  = threadIdx.x;
    const int wv   = tid >> 6, lane = tid & 63;
    const int n    = lane & 15, q = lane >> 4;
    const int oct  = (q & 1) * 8;
    const bool sel = (q < 2);
    const f32x4 zero = {0.f, 0.f, 0.f, 0.f};

    // p-write phase mapping: thread -> (k = tid/4, b0 = (tid&3)*8)
    const int pk = tid >> 2;
    const int pb = (tid & 3) * 8;

    const int i0 = blockIdx.x * 4;
#pragma unroll 1
    for (int ii = 0; ii < 4; ++ii) {
        const int i = i0 + ii;
        s16x8 X1[2], X2[2];
        if constexpr (PK) {
            const s16x8* xp = xA + ((size_t)i * 2 * 64 + lane) * 2;
            X1[0] = xp[0];   X2[0] = xp[1];
            X1[1] = xp[128]; X2[1] = xp[129];
        } else {
#pragma unroll
            for (int bg = 0; bg < 2; ++bg)
                pack_A(x + ((size_t)(bg * 16 + n) * 2048 + i) * 16 + oct, X1[bg], X2[bg]);
        }

        float den0 = 0.f, den1 = 0.f;
#pragma unroll
        for (int kp = 0; kp < 16; ++kp) {
            const int k = wv * 16 + kp;
            const s16x8 Wf = PK ? Wp[((size_t)i * 128 + k) * 64 + lane]
                                : pack_B(W + (size_t)i * 32768 + (size_t)k * 256 + n * 16 + oct, sel);
            float ebg[2];
#pragma unroll
            for (int bg = 0; bg < 2; ++bg) {
                f32x4 u = __builtin_amdgcn_mfma_f32_16x16x32_bf16(Wf, X1[bg], zero, 0, 0, 0);
                u       = __builtin_amdgcn_mfma_f32_16x16x32_bf16(Wf, X2[bg], u,    0, 0, 0);
                const float4 Vv = *(const float4*)(Vq + (((size_t)k * 4 + q) * 32 + bg * 16 + n) * 4);
                float s2 = u.x * u.x;
                s2 = fmaf(u.y, u.y, s2);
                s2 = fmaf(u.z, u.z, s2);
                s2 = fmaf(u.w, u.w, s2);
                float dt = u.x * Vv.x;
                dt = fmaf(u.y, Vv.y, dt);
                dt = fmaf(u.z, Vv.z, dt);
                dt = fmaf(u.w, Vv.w, dt);
                s2 += __shfl_xor(s2, 16, 64);
                s2 += __shfl_xor(s2, 32, 64);
                dt += __shfl_xor(dt, 16, 64);
                dt += __shfl_xor(dt, 32, 64);
                const float Nr  = Nt[(size_t)k * 32 + bg * 16 + n];
                const float inv = 1.0f / (0.5f + s2);
                const float scl = sqrtf(s2) * inv;
                const float fq  = s2 * s2 * inv * inv;
                const float e   = __expf(T * (1.0f - fq) + 2.0f * scl * dt - Nr);
                if (bg == 0) den0 += e; else den1 += e;
                ebg[bg] = e;
            }
            if (lane < 16) {
                e_s[wv][kp][n]      = ebg[0];
                e_s[wv][kp][16 + n] = ebg[1];
            }
        }
        if (lane < 16) {
            den_s[wv][n]      = den0;
            den_s[wv][16 + n] = den1;
        }
        __syncthreads();
        if (tid < 32) {
            float s = 0.f;
#pragma unroll
            for (int w2 = 0; w2 < 8; ++w2) s += den_s[w2][tid];
            denom_s[tid] = s;
        }
        __syncthreads();
        {
            const float4 e0 = *(const float4*)&e_s[pk >> 4][pk & 15][pb];
            const float4 e1 = *(const float4*)&e_s[pk >> 4][pk & 15][pb + 4];
            const float4 d0 = *(const float4*)&denom_s[pb];
            const float4 d1 = *(const float4*)&denom_s[pb + 4];
            float4 p0, p1;
            p0.x = e0.x / d0.x; p0.y = e0.y / d0.y; p0.z = e0.z / d0.z; p0.w = e0.w / d0.w;
            p1.x = e1.x / d1.x; p1.y = e1.y / d1.y; p1.z = e1.z / d1.z; p1.w = e1.w / d1.w;
            *(float4*)(pbuf + ((size_t)i * 128 + pk) * 32 + pb)     = p0;
            *(float4*)(pbuf + ((size_t)i * 128 + pk) * 32 + pb + 4) = p1;
        }
        __syncthreads();
    }
}

// ---------------------------------------------------------------------------
// Sum 64 slices (+ colsum partials) -> v = squash(raw/colsum); write transposed
// tables (mode 0/1, V in [k][d>>2][b][d&3] layout) or output (mode 2).
__global__ __launch_bounds__(256) void k_fin(const float* __restrict__ raw_sl,
                                             const float* __restrict__ csl,   // [s][k][b]
                                             const float* __restrict__ Vq_prev,
                                             const float* __restrict__ Nt_prev,
                                             float* __restrict__ Vq_out,
                                             float* __restrict__ Nt_out,
                                             float* __restrict__ out,
                                             const int mode)
{
    const int tid = threadIdx.x;
    const int t   = blockIdx.x * 16 + (tid >> 4);   // (b,k): b=t>>7, k=t&127
    const int d   = tid & 15;
    const int b   = t >> 7, k = t & 127;
    float s = 0.f, cs = 0.f;
    if (mode == 0) {
#pragma unroll 4
        for (int sl = 0; sl < NSLICE; ++sl) s += raw_sl[(size_t)sl * 65536 + (size_t)t * 16 + d];
    } else {
#pragma unroll 4
        for (int sl = 0; sl < NSLICE; ++sl) {
            s  += raw_sl[(size_t)sl * 65536 + (size_t)t * 16 + d];
            cs += csl[(size_t)sl * 4096 + k * 32 + b];
        }
    }
    const float invcs = (mode == 0) ? (1.0f / 2048.0f) : 1.0f / cs;
    const float v = s * invcs;
    float s2 = v * v;
#pragma unroll
    for (int m = 1; m < 16; m <<= 1) s2 += __shfl_xor(s2, m, 64);
    const float inv = 1.0f / (0.5f + s2);
    const float scl = sqrtf(s2) * inv;
    const size_t vidx = (((size_t)k * 4 + (d >> 2)) * 32 + b) * 4 + (d & 3);
    if (mode == 0) {
        Vq_out[vidx] = scl * v;
        if (d == 0) Nt_out[(size_t)k * 32 + b] = s2 * scl * scl;
    } else if (mode == 1) {
        Vq_out[vidx] = Vq_prev[vidx] + scl * v;
        if (d == 0) Nt_out[(size_t)k * 32 + b] = Nt_prev[(size_t)k * 32 + b] + s2 * scl * scl;
    } else {
        out[(size_t)t * 16 + d] = scl * v;
        if (d == 0) out[65536 + t] = s2 * inv;   // ||v|| = s2/(0.5+s2)
    }
}

extern "C" void kernel_launch(void* const* d_in, const int* in_sizes, int n_in,
                              void* d_out, int out_size, void* d_ws, size_t ws_size,
                              hipStream_t stream)
{
    const float* x = (const float*)d_in[0];   // [32][2048][16]
    const float* W = (const float*)d_in[3];   // [2048][128][16][16]; labels = arange -> identity

    float* ws    = (float*)d_ws;
    float* Vbt0  = ws;                 // 65536  [k][d>>2][b][d&3]
    float* VSbt  = ws + 65536;         // 65536
    float* N1t   = ws + 131072;        // 4096   [k][b]
    float* N2t   = ws + 135168;        // 4096
    float* csl   = ws + 139264;        // 262144 (1MB) [s][k][b]
    float* pbuf  = ws + 401408;        // 8388608 (32MB) [i][k][b]
    float* slces = ws + 8790016;       // 4194304 (16MB) [s][b][k][d]

    // packed fragment tables (appended; 16B-aligned)
    s16x8* Wp = (s16x8*)(ws + 12984320);                       // 268MB: 262144*64 frags
    s16x8* xA = (s16x8*)((short*)Wp + (size_t)134217728);      // 16MB:  4096*64*2 frags
    const size_t needed = (size_t)12984320 * 4
                        + (size_t)134217728 * 2
                        + (size_t)8388608 * 2;
    const bool pk = (ws_size >= needed);

    if (pk) {
        k_packW<<<65536, 256, 0, stream>>>(W, Wp);
        k_packX<<<1024, 256, 0, stream>>>(x, xA);
        // iter 0: v0 = squash(mean_i u_hat)
        k_acc<false, true><<<1024, 256, 0, stream>>>(W, x, Wp, xA, nullptr, slces, nullptr);
        k_fin<<<256, 256, 0, stream>>>(slces, nullptr, nullptr, nullptr, Vbt0, N1t, nullptr, 0);
        // iter 1
        k_logits<true><<<512, 512, 0, stream>>>(W, x, Wp, xA, Vbt0, N1t, 1.0f, pbuf);
        k_acc<true, true><<<1024, 256, 0, stream>>>(W, x, Wp, xA, pbuf, slces, csl);
        k_fin<<<256, 256, 0, stream>>>(slces, csl, Vbt0, N1t, VSbt, N2t, nullptr, 1);
        // iter 2: b2 = dd0+dd1 via summed tables VS=v0+v1, N2=||v0||^2+||v1||^2
        k_logits<true><<<512, 512, 0, stream>>>(W, x, Wp, xA, VSbt, N2t, 2.0f, pbuf);
        k_acc<true, true><<<1024, 256, 0, stream>>>(W, x, Wp, xA, pbuf, slces, csl);
        k_fin<<<256, 256, 0, stream>>>(slces, csl, nullptr, nullptr, nullptr, nullptr, (float*)d_out, 2);
    } else {
        // fallback: in-kernel packing (identical numerics, same swapped structure)
        k_acc<false, false><<<1024, 256, 0, stream>>>(W, x, nullptr, nullptr, nullptr, slces, nullptr);
        k_fin<<<256, 256, 0, stream>>>(slces, nullptr, nullptr, nullptr, Vbt0, N1t, nullptr, 0);
        k_logits<false><<<512, 512, 0, stream>>>(W, x, nullptr, nullptr, Vbt0, N1t, 1.0f, pbuf);
        k_acc<true, false><<<1024, 256, 0, stream>>>(W, x, nullptr, nullptr, pbuf, slces, csl);
        k_fin<<<256, 256, 0, stream>>>(slces, csl, Vbt0, N1t, VSbt, N2t, nullptr, 1);
        k_logits<false><<<512, 512, 0, stream>>>(W, x, nullptr, nullptr, VSbt, N2t, 2.0f, pbuf);
        k_acc<true, false><<<1024, 256, 0, stream>>>(W, x, nullptr, nullptr, pbuf, slces, csl);
        k_fin<<<256, 256, 0, stream>>>(slces, csl, nullptr, nullptr, nullptr, nullptr, (float*)d_out, 2);
    }
}

// Round 4
// 780.884 us; speedup vs baseline: 1.7950x; 1.0992x over previous
//
#include <hip/hip_runtime.h>

// B=32, N_IN=2048, K_OUT=128, C=16, D=16, 3 routing iters.
// Structure (packed path):
//   k_packX   : x -> per-lane MFMA A-frags (hi/lo)
//   k_packWacc: W -> per-lane B-frags written to Wp  +  iter-0 unweighted MFMA
//               accumulation (mean u_hat) fused in the same pass (saves a full
//               268MB Wp read vs separate k_packW + k_acc<false>).
//   per iter  : k_logits (MFMA u tiles -> softmax p) ; k_acc (software-pipelined
//               MFMA weighted sum -> slice partials + colsum partials) ; k_fin.
// MFMA hi/lo trick (verified R3): K=32 packed as [c_hi | c_lo].
// Swapped operands (verified R1->R2): u[d][b] = mfma(Wfrag, xfrag); d-reduction is
// 4 in-lane fmas + xor16 + xor32 shuffles. No atomics anywhere.
// V table stored as [k][d>>2][b][d&3] so each lane's 4 d-values load as one float4.
// NOTE: no second __launch_bounds__ arg anywhere -- it acts as a hard VGPR cap.

typedef __attribute__((ext_vector_type(8))) short  s16x8;
typedef __attribute__((ext_vector_type(4))) float  f32x4;

#define NSLICE 64

__device__ __forceinline__ unsigned bf16rn(float f) {
    const unsigned u = __builtin_bit_cast(unsigned, f);
    return (u + 0x7fffu + ((u >> 16) & 1u)) >> 16;
}
__device__ __forceinline__ unsigned pack2rn(float a, float b) {
    return bf16rn(a) | (bf16rn(b) << 16);
}
__device__ __forceinline__ unsigned phi(float a, float b) {   // truncation hi-pack
    return (__builtin_bit_cast(unsigned, a) >> 16) | (__builtin_bit_cast(unsigned, b) & 0xffff0000u);
}
__device__ __forceinline__ unsigned plo(float a, float b) {   // residual lo-pack
    const float la = a - __builtin_bit_cast(float, __builtin_bit_cast(unsigned, a) & 0xffff0000u);
    const float lb = b - __builtin_bit_cast(float, __builtin_bit_cast(unsigned, b) & 0xffff0000u);
    return pack2rn(la, lb);
}

// x-frags for one b-group: X1=[x_hi|x_hi], X2=[x_lo|x_lo]; xp points at x[b][i][oct]
__device__ __forceinline__ void pack_A(const float* __restrict__ xp, s16x8& A1, s16x8& A2) {
    const float4 x0 = *(const float4*)xp;
    const float4 x1 = *(const float4*)(xp + 4);
    uint4 h, l;
    h.x = phi(x0.x, x0.y); h.y = phi(x0.z, x0.w);
    h.z = phi(x1.x, x1.y); h.w = phi(x1.z, x1.w);
    l.x = plo(x0.x, x0.y); l.y = plo(x0.z, x0.w);
    l.z = plo(x1.x, x1.y); l.w = plo(x1.z, x1.w);
    A1 = __builtin_bit_cast(s16x8, h);
    A2 = __builtin_bit_cast(s16x8, l);
}

// W-frag pack from preloaded raw float4s: [W_hi|W_lo], sel=true -> hi half lanes
__device__ __forceinline__ s16x8 pack_B_f(const float4 w0, const float4 w1, bool sel) {
    const float f[8] = {w0.x, w0.y, w0.z, w0.w, w1.x, w1.y, w1.z, w1.w};
    float t[8];
#pragma unroll
    for (int j = 0; j < 8; ++j) {
        const float hf = __builtin_bit_cast(float, __builtin_bit_cast(unsigned, f[j]) & 0xffff0000u);
        t[j] = sel ? hf : (f[j] - hf);
    }
    uint4 bw;
    bw.x = pack2rn(t[0], t[1]);
    bw.y = pack2rn(t[2], t[3]);
    bw.z = pack2rn(t[4], t[5]);
    bw.w = pack2rn(t[6], t[7]);
    return __builtin_bit_cast(s16x8, bw);
}
__device__ __forceinline__ s16x8 pack_B(const float* __restrict__ wp, bool sel) {
    return pack_B_f(*(const float4*)wp, *(const float4*)(wp + 4), sel);
}

// ---------------------------------------------------------------------------
__global__ __launch_bounds__(256) void k_packX(const float* __restrict__ x,
                                               s16x8* __restrict__ xA)
{
    const int wid  = blockIdx.x * 4 + (threadIdx.x >> 6);   // 0..4095 = i*2+bg
    const int lane = threadIdx.x & 63;
    const int i  = wid >> 1, bg = wid & 1;
    const int n  = lane & 15, q = lane >> 4;
    const int oct = (q & 1) * 8;
    s16x8 A1, A2;
    pack_A(x + ((size_t)(bg * 16 + n) * 2048 + i) * 16 + oct, A1, A2);
    s16x8* o = xA + ((size_t)wid * 64 + lane) * 2;
    o[0] = A1;
    o[1] = A2;
}

// ---------------------------------------------------------------------------
// Fused W-pack + iter0 accumulation. Wave = (slice, k-pair) like k_acc:
// packs W[i][k] -> Wp (for all later passes) AND accumulates the unweighted
// mean-u partials for this slice in the same registers. Software-pipelined.
__global__ __launch_bounds__(256) void k_packWacc(const float* __restrict__ W,
                                                  const s16x8* __restrict__ xA,
                                                  s16x8* __restrict__ Wp,
                                                  float* __restrict__ out_sl)   // [s][b][k][d]
{
    const int w    = blockIdx.x * 4 + (threadIdx.x >> 6);   // 0..4095
    const int lane = threadIdx.x & 63;
    const int n    = lane & 15;
    const int q    = lane >> 4;
    const int oct  = (q & 1) * 8;
    const bool sel = (q < 2);
    const int k0    = (w & 63) * 2;
    const int slice = w >> 6;
    const int i0    = slice * 32;

    const f32x4 zero = {0.f, 0.f, 0.f, 0.f};
    f32x4 acc[2][2];
#pragma unroll
    for (int kp = 0; kp < 2; ++kp)
#pragma unroll
        for (int bg = 0; bg < 2; ++bg) acc[kp][bg] = zero;

    // preload i0
    float4 rw0[2], rw1[2];
    s16x8 X1c[2], X2c[2];
    {
        const float* wp_ = W + (size_t)i0 * 32768 + (size_t)k0 * 256 + n * 16 + oct;
        rw0[0] = *(const float4*)wp_;          rw1[0] = *(const float4*)(wp_ + 4);
        rw0[1] = *(const float4*)(wp_ + 256);  rw1[1] = *(const float4*)(wp_ + 260);
        const s16x8* xp = xA + (size_t)i0 * 256 + (size_t)lane * 2;
        X1c[0] = xp[0];   X2c[0] = xp[1];
        X1c[1] = xp[128]; X2c[1] = xp[129];
    }

#pragma unroll 1
    for (int i = i0; i < i0 + 32; ++i) {
        const int in_ = (i + 1 < i0 + 32) ? i + 1 : i;
        // issue next-iteration loads first (hide HBM latency under pack+MFMA)
        float4 nw0[2], nw1[2];
        s16x8 X1n[2], X2n[2];
        {
            const float* wp_ = W + (size_t)in_ * 32768 + (size_t)k0 * 256 + n * 16 + oct;
            nw0[0] = *(const float4*)wp_;          nw1[0] = *(const float4*)(wp_ + 4);
            nw0[1] = *(const float4*)(wp_ + 256);  nw1[1] = *(const float4*)(wp_ + 260);
            const s16x8* xp = xA + (size_t)in_ * 256 + (size_t)lane * 2;
            X1n[0] = xp[0];   X2n[0] = xp[1];
            X1n[1] = xp[128]; X2n[1] = xp[129];
        }
#pragma unroll
        for (int kp = 0; kp < 2; ++kp) {
            const s16x8 Wf = pack_B_f(rw0[kp], rw1[kp], sel);
            Wp[((size_t)i * 128 + (k0 + kp)) * 64 + lane] = Wf;
#pragma unroll
            for (int bg = 0; bg < 2; ++bg) {
                acc[kp][bg] = __builtin_amdgcn_mfma_f32_16x16x32_bf16(Wf, X1c[bg], acc[kp][bg], 0, 0, 0);
                acc[kp][bg] = __builtin_amdgcn_mfma_f32_16x16x32_bf16(Wf, X2c[bg], acc[kp][bg], 0, 0, 0);
            }
        }
#pragma unroll
        for (int kp = 0; kp < 2; ++kp) { rw0[kp] = nw0[kp]; rw1[kp] = nw1[kp]; }
#pragma unroll
        for (int bg = 0; bg < 2; ++bg) { X1c[bg] = X1n[bg]; X2c[bg] = X2n[bg]; }
    }
#pragma unroll
    for (int kp = 0; kp < 2; ++kp)
#pragma unroll
        for (int bg = 0; bg < 2; ++bg)
            *(f32x4*)(out_sl + (((size_t)slice * 32 + bg * 16 + n) * 128 + (k0 + kp)) * 16 + 4 * q)
                = acc[kp][bg];
}

// ---------------------------------------------------------------------------
// out_sl[s][b][k][d] = sum_{i in slice s} w(b,i,k)*u_hat(b,i,k,d); w=p or 1.
// Swapped: u tile is [d][b]; lane (q,n) holds d=4q+r (r=0..3), b=n (+16 for bg=1).
// PK path is software-pipelined (loads for i+1 issued before compute of i).
template<bool USE_P, bool PK>
__global__ __launch_bounds__(256) void k_acc(const float* __restrict__ W,
                                             const float* __restrict__ x,
                                             const s16x8* __restrict__ Wp,
                                             const s16x8* __restrict__ xA,
                                             const float* __restrict__ p,     // [i][k][b]
                                             float* __restrict__ out_sl,      // [s][b][k][d]
                                             float* __restrict__ csl)         // [s][k][b]
{
    const int w    = blockIdx.x * 4 + (threadIdx.x >> 6);   // 0..4095
    const int lane = threadIdx.x & 63;
    const int n    = lane & 15;
    const int q    = lane >> 4;
    const int oct  = (q & 1) * 8;
    const bool sel = (q < 2);
    const int k0    = (w & 63) * 2;
    const int slice = w >> 6;
    const int i0    = slice * 32;

    const f32x4 zero = {0.f, 0.f, 0.f, 0.f};
    f32x4 acc[2][2];
    float csacc[2][2];
#pragma unroll
    for (int kp = 0; kp < 2; ++kp)
#pragma unroll
        for (int bg = 0; bg < 2; ++bg) { acc[kp][bg] = zero; csacc[kp][bg] = 0.f; }

    if constexpr (PK) {
        // preload i0
        s16x8 X1c[2], X2c[2], Wc[2];
        float pc[2][2];
        {
            const s16x8* xp = xA + (size_t)i0 * 256 + (size_t)lane * 2;
            X1c[0] = xp[0];   X2c[0] = xp[1];
            X1c[1] = xp[128]; X2c[1] = xp[129];
            Wc[0] = Wp[((size_t)i0 * 128 + k0) * 64 + lane];
            Wc[1] = Wp[((size_t)i0 * 128 + k0 + 1) * 64 + lane];
            if (USE_P) {
#pragma unroll
                for (int kp = 0; kp < 2; ++kp)
#pragma unroll
                    for (int bg = 0; bg < 2; ++bg)
                        pc[kp][bg] = p[((size_t)i0 * 128 + k0 + kp) * 32 + bg * 16 + n];
            }
        }
#pragma unroll 1
        for (int i = i0; i < i0 + 32; ++i) {
            const int in_ = (i + 1 < i0 + 32) ? i + 1 : i;
            s16x8 X1n[2], X2n[2], Wn[2];
            float pn[2][2];
            {
                const s16x8* xp = xA + (size_t)in_ * 256 + (size_t)lane * 2;
                X1n[0] = xp[0];   X2n[0] = xp[1];
                X1n[1] = xp[128]; X2n[1] = xp[129];
                Wn[0] = Wp[((size_t)in_ * 128 + k0) * 64 + lane];
                Wn[1] = Wp[((size_t)in_ * 128 + k0 + 1) * 64 + lane];
                if (USE_P) {
#pragma unroll
                    for (int kp = 0; kp < 2; ++kp)
#pragma unroll
                        for (int bg = 0; bg < 2; ++bg)
                            pn[kp][bg] = p[((size_t)in_ * 128 + k0 + kp) * 32 + bg * 16 + n];
                }
            }
#pragma unroll
            for (int kp = 0; kp < 2; ++kp) {
#pragma unroll
                for (int bg = 0; bg < 2; ++bg) {
                    if (USE_P) {
                        f32x4 u = __builtin_amdgcn_mfma_f32_16x16x32_bf16(Wc[kp], X1c[bg], zero, 0, 0, 0);
                        u       = __builtin_amdgcn_mfma_f32_16x16x32_bf16(Wc[kp], X2c[bg], u,    0, 0, 0);
                        const float pv = pc[kp][bg];
                        acc[kp][bg].x = fmaf(pv, u.x, acc[kp][bg].x);
                        acc[kp][bg].y = fmaf(pv, u.y, acc[kp][bg].y);
                        acc[kp][bg].z = fmaf(pv, u.z, acc[kp][bg].z);
                        acc[kp][bg].w = fmaf(pv, u.w, acc[kp][bg].w);
                        csacc[kp][bg] += pv;
                    } else {
                        acc[kp][bg] = __builtin_amdgcn_mfma_f32_16x16x32_bf16(Wc[kp], X1c[bg], acc[kp][bg], 0, 0, 0);
                        acc[kp][bg] = __builtin_amdgcn_mfma_f32_16x16x32_bf16(Wc[kp], X2c[bg], acc[kp][bg], 0, 0, 0);
                    }
                }
            }
#pragma unroll
            for (int kp = 0; kp < 2; ++kp) Wc[kp] = Wn[kp];
#pragma unroll
            for (int bg = 0; bg < 2; ++bg) { X1c[bg] = X1n[bg]; X2c[bg] = X2n[bg]; }
            if (USE_P) {
#pragma unroll
                for (int kp = 0; kp < 2; ++kp)
#pragma unroll
                    for (int bg = 0; bg < 2; ++bg) pc[kp][bg] = pn[kp][bg];
            }
        }
    } else {
#pragma unroll 1
        for (int i = i0; i < i0 + 32; ++i) {
            s16x8 X1[2], X2[2];
#pragma unroll
            for (int bg = 0; bg < 2; ++bg)
                pack_A(x + ((size_t)(bg * 16 + n) * 2048 + i) * 16 + oct, X1[bg], X2[bg]);
#pragma unroll
            for (int kp = 0; kp < 2; ++kp) {
                const int k = k0 + kp;
                const s16x8 Wf = pack_B(W + (size_t)i * 32768 + (size_t)k * 256 + n * 16 + oct, sel);
#pragma unroll
                for (int bg = 0; bg < 2; ++bg) {
                    if (USE_P) {
                        f32x4 u = __builtin_amdgcn_mfma_f32_16x16x32_bf16(Wf, X1[bg], zero, 0, 0, 0);
                        u       = __builtin_amdgcn_mfma_f32_16x16x32_bf16(Wf, X2[bg], u,    0, 0, 0);
                        const float pv = p[((size_t)i * 128 + k) * 32 + bg * 16 + n];
                        acc[kp][bg].x = fmaf(pv, u.x, acc[kp][bg].x);
                        acc[kp][bg].y = fmaf(pv, u.y, acc[kp][bg].y);
                        acc[kp][bg].z = fmaf(pv, u.z, acc[kp][bg].z);
                        acc[kp][bg].w = fmaf(pv, u.w, acc[kp][bg].w);
                        csacc[kp][bg] += pv;
                    } else {
                        acc[kp][bg] = __builtin_amdgcn_mfma_f32_16x16x32_bf16(Wf, X1[bg], acc[kp][bg], 0, 0, 0);
                        acc[kp][bg] = __builtin_amdgcn_mfma_f32_16x16x32_bf16(Wf, X2[bg], acc[kp][bg], 0, 0, 0);
                    }
                }
            }
        }
    }
#pragma unroll
    for (int kp = 0; kp < 2; ++kp)
#pragma unroll
        for (int bg = 0; bg < 2; ++bg)
            *(f32x4*)(out_sl + (((size_t)slice * 32 + bg * 16 + n) * 128 + (k0 + kp)) * 16 + 4 * q)
                = acc[kp][bg];
    if (USE_P && lane < 16) {
#pragma unroll
        for (int kp = 0; kp < 2; ++kp)
#pragma unroll
            for (int bg = 0; bg < 2; ++bg)
                csl[((size_t)slice * 128 + (k0 + kp)) * 32 + bg * 16 + n] = csacc[kp][bg];
    }
}

// ---------------------------------------------------------------------------
// MFMA logits (swapped): block = 8 waves, wave wv covers k = wv*16+kp, 4 i's per block.
// Rotating Wf prefetch across kp. No atomics.
template<bool PK>
__global__ __launch_bounds__(512) void k_logits(const float* __restrict__ W,
                                                const float* __restrict__ x,
                                                const s16x8* __restrict__ Wp,
                                                const s16x8* __restrict__ xA,
                                                const float* __restrict__ Vq,   // [k][d>>2][b][d&3]
                                                const float* __restrict__ Nt,   // [k][b]
                                                const float T,
                                                float* __restrict__ pbuf)       // [i][k][b]
{
    __shared__ __align__(16) float e_s[8][16][32];
    __shared__ __align__(16) float den_s[8][32];
    __shared__ float denom_s[32];
    const int tid  = threadIdx.x;
    const int wv   = tid >> 6, lane = tid & 63;
    const int n    = lane & 15, q = lane >> 4;
    const int oct  = (q & 1) * 8;
    const bool sel = (q < 2);
    const f32x4 zero = {0.f, 0.f, 0.f, 0.f};

    const int pk = tid >> 2;
    const int pb = (tid & 3) * 8;

    const int i0 = blockIdx.x * 4;
#pragma unroll 1
    for (int ii = 0; ii < 4; ++ii) {
        const int i = i0 + ii;
        s16x8 X1[2], X2[2];
        if constexpr (PK) {
            const s16x8* xp = xA + (size_t)i * 256 + (size_t)lane * 2;
            X1[0] = xp[0];   X2[0] = xp[1];
            X1[1] = xp[128]; X2[1] = xp[129];
        } else {
#pragma unroll
            for (int bg = 0; bg < 2; ++bg)
                pack_A(x + ((size_t)(bg * 16 + n) * 2048 + i) * 16 + oct, X1[bg], X2[bg]);
        }

        float den0 = 0.f, den1 = 0.f;
        s16x8 Wf;
        if constexpr (PK) Wf = Wp[((size_t)i * 128 + wv * 16) * 64 + lane];
#pragma unroll
        for (int kp = 0; kp < 16; ++kp) {
            const int k = wv * 16 + kp;
            if constexpr (!PK) {
                Wf = pack_B(W + (size_t)i * 32768 + (size_t)k * 256 + n * 16 + oct, sel);
            }
            s16x8 Wfn;
            if constexpr (PK) {
                const int kn = (kp < 15) ? k + 1 : k;
                Wfn = Wp[((size_t)i * 128 + kn) * 64 + lane];
            }
            float ebg[2];
#pragma unroll
            for (int bg = 0; bg < 2; ++bg) {
                f32x4 u = __builtin_amdgcn_mfma_f32_16x16x32_bf16(Wf, X1[bg], zero, 0, 0, 0);
                u       = __builtin_amdgcn_mfma_f32_16x16x32_bf16(Wf, X2[bg], u,    0, 0, 0);
                const float4 Vv = *(const float4*)(Vq + (((size_t)k * 4 + q) * 32 + bg * 16 + n) * 4);
                float s2 = u.x * u.x;
                s2 = fmaf(u.y, u.y, s2);
                s2 = fmaf(u.z, u.z, s2);
                s2 = fmaf(u.w, u.w, s2);
                float dt = u.x * Vv.x;
                dt = fmaf(u.y, Vv.y, dt);
                dt = fmaf(u.z, Vv.z, dt);
                dt = fmaf(u.w, Vv.w, dt);
                s2 += __shfl_xor(s2, 16, 64);
                s2 += __shfl_xor(s2, 32, 64);
                dt += __shfl_xor(dt, 16, 64);
                dt += __shfl_xor(dt, 32, 64);
                const float Nr  = Nt[(size_t)k * 32 + bg * 16 + n];
                const float inv = 1.0f / (0.5f + s2);
                const float scl = sqrtf(s2) * inv;
                const float fq  = s2 * s2 * inv * inv;
                const float e   = __expf(T * (1.0f - fq) + 2.0f * scl * dt - Nr);
                if (bg == 0) den0 += e; else den1 += e;
                ebg[bg] = e;
            }
            if (lane < 16) {
                e_s[wv][kp][n]      = ebg[0];
                e_s[wv][kp][16 + n] = ebg[1];
            }
            if constexpr (PK) Wf = Wfn;
        }
        if (lane < 16) {
            den_s[wv][n]      = den0;
            den_s[wv][16 + n] = den1;
        }
        __syncthreads();
        if (tid < 32) {
            float s = 0.f;
#pragma unroll
            for (int w2 = 0; w2 < 8; ++w2) s += den_s[w2][tid];
            denom_s[tid] = s;
        }
        __syncthreads();
        {
            const float4 e0 = *(const float4*)&e_s[pk >> 4][pk & 15][pb];
            const float4 e1 = *(const float4*)&e_s[pk >> 4][pk & 15][pb + 4];
            const float4 d0 = *(const float4*)&denom_s[pb];
            const float4 d1 = *(const float4*)&denom_s[pb + 4];
            float4 p0, p1;
            p0.x = e0.x / d0.x; p0.y = e0.y / d0.y; p0.z = e0.z / d0.z; p0.w = e0.w / d0.w;
            p1.x = e1.x / d1.x; p1.y = e1.y / d1.y; p1.z = e1.z / d1.z; p1.w = e1.w / d1.w;
            *(float4*)(pbuf + ((size_t)i * 128 + pk) * 32 + pb)     = p0;
            *(float4*)(pbuf + ((size_t)i * 128 + pk) * 32 + pb + 4) = p1;
        }
        __syncthreads();
    }
}

// ---------------------------------------------------------------------------
// Sum 64 slices (+ colsum partials) -> v = squash(raw/colsum); write transposed
// tables (mode 0/1, V in [k][d>>2][b][d&3] layout) or output (mode 2).
__global__ __launch_bounds__(256) void k_fin(const float* __restrict__ raw_sl,
                                             const float* __restrict__ csl,   // [s][k][b]
                                             const float* __restrict__ Vq_prev,
                                             const float* __restrict__ Nt_prev,
                                             float* __restrict__ Vq_out,
                                             float* __restrict__ Nt_out,
                                             float* __restrict__ out,
                                             const int mode)
{
    const int tid = threadIdx.x;
    const int t   = blockIdx.x * 16 + (tid >> 4);   // (b,k): b=t>>7, k=t&127
    const int d   = tid & 15;
    const int b   = t >> 7, k = t & 127;
    float s = 0.f, cs = 0.f;
    if (mode == 0) {
#pragma unroll 4
        for (int sl = 0; sl < NSLICE; ++sl) s += raw_sl[(size_t)sl * 65536 + (size_t)t * 16 + d];
    } else {
#pragma unroll 4
        for (int sl = 0; sl < NSLICE; ++sl) {
            s  += raw_sl[(size_t)sl * 65536 + (size_t)t * 16 + d];
            cs += csl[(size_t)sl * 4096 + k * 32 + b];
        }
    }
    const float invcs = (mode == 0) ? (1.0f / 2048.0f) : 1.0f / cs;
    const float v = s * invcs;
    float s2 = v * v;
#pragma unroll
    for (int m = 1; m < 16; m <<= 1) s2 += __shfl_xor(s2, m, 64);
    const float inv = 1.0f / (0.5f + s2);
    const float scl = sqrtf(s2) * inv;
    const size_t vidx = (((size_t)k * 4 + (d >> 2)) * 32 + b) * 4 + (d & 3);
    if (mode == 0) {
        Vq_out[vidx] = scl * v;
        if (d == 0) Nt_out[(size_t)k * 32 + b] = s2 * scl * scl;
    } else if (mode == 1) {
        Vq_out[vidx] = Vq_prev[vidx] + scl * v;
        if (d == 0) Nt_out[(size_t)k * 32 + b] = Nt_prev[(size_t)k * 32 + b] + s2 * scl * scl;
    } else {
        out[(size_t)t * 16 + d] = scl * v;
        if (d == 0) out[65536 + t] = s2 * inv;   // ||v|| = s2/(0.5+s2)
    }
}

extern "C" void kernel_launch(void* const* d_in, const int* in_sizes, int n_in,
                              void* d_out, int out_size, void* d_ws, size_t ws_size,
                              hipStream_t stream)
{
    const float* x = (const float*)d_in[0];   // [32][2048][16]
    const float* W = (const float*)d_in[3];   // [2048][128][16][16]; labels = arange -> identity

    float* ws    = (float*)d_ws;
    float* Vbt0  = ws;                 // 65536  [k][d>>2][b][d&3]
    float* VSbt  = ws + 65536;         // 65536
    float* N1t   = ws + 131072;        // 4096   [k][b]
    float* N2t   = ws + 135168;        // 4096
    float* csl   = ws + 139264;        // 262144 (1MB) [s][k][b]
    float* pbuf  = ws + 401408;        // 8388608 (32MB) [i][k][b]
    float* slces = ws + 8790016;       // 4194304 (16MB) [s][b][k][d]

    // packed fragment tables (appended; 16B-aligned)
    s16x8* Wp = (s16x8*)(ws + 12984320);                       // 268MB: 262144*64 frags
    s16x8* xA = (s16x8*)((short*)Wp + (size_t)134217728);      // 16MB:  4096*64*2 frags
    const size_t needed = (size_t)12984320 * 4
                        + (size_t)134217728 * 2
                        + (size_t)8388608 * 2;
    const bool pk = (ws_size >= needed);

    if (pk) {
        k_packX<<<1024, 256, 0, stream>>>(x, xA);
        // pack W + iter0 (v0 = squash(mean_i u_hat)) in one pass over W
        k_packWacc<<<1024, 256, 0, stream>>>(W, xA, Wp, slces);
        k_fin<<<256, 256, 0, stream>>>(slces, nullptr, nullptr, nullptr, Vbt0, N1t, nullptr, 0);
        // iter 1
        k_logits<true><<<512, 512, 0, stream>>>(W, x, Wp, xA, Vbt0, N1t, 1.0f, pbuf);
        k_acc<true, true><<<1024, 256, 0, stream>>>(W, x, Wp, xA, pbuf, slces, csl);
        k_fin<<<256, 256, 0, stream>>>(slces, csl, Vbt0, N1t, VSbt, N2t, nullptr, 1);
        // iter 2: b2 = dd0+dd1 via summed tables VS=v0+v1, N2=||v0||^2+||v1||^2
        k_logits<true><<<512, 512, 0, stream>>>(W, x, Wp, xA, VSbt, N2t, 2.0f, pbuf);
        k_acc<true, true><<<1024, 256, 0, stream>>>(W, x, Wp, xA, pbuf, slces, csl);
        k_fin<<<256, 256, 0, stream>>>(slces, csl, nullptr, nullptr, nullptr, nullptr, (float*)d_out, 2);
    } else {
        // fallback: in-kernel packing (identical numerics, same swapped structure)
        k_acc<false, false><<<1024, 256, 0, stream>>>(W, x, nullptr, nullptr, nullptr, slces, nullptr);
        k_fin<<<256, 256, 0, stream>>>(slces, nullptr, nullptr, nullptr, Vbt0, N1t, nullptr, 0);
        k_logits<false><<<512, 512, 0, stream>>>(W, x, nullptr, nullptr, Vbt0, N1t, 1.0f, pbuf);
        k_acc<true, false><<<1024, 256, 0, stream>>>(W, x, nullptr, nullptr, pbuf, slces, csl);
        k_fin<<<256, 256, 0, stream>>>(slces, csl, Vbt0, N1t, VSbt, N2t, nullptr, 1);
        k_logits<false><<<512, 512, 0, stream>>>(W, x, nullptr, nullptr, VSbt, N2t, 2.0f, pbuf);
        k_acc<true, false><<<1024, 256, 0, stream>>>(W, x, nullptr, nullptr, pbuf, slces, csl);
        k_fin<<<256, 256, 0, stream>>>(slces, csl, nullptr, nullptr, nullptr, nullptr, (float*)d_out, 2);
    }
}